// Round 4
// baseline (493.134 us; speedup 1.0000x reference)
//
#include <hip/hip_runtime.h>
#include <hip/hip_bf16.h>
#include <stdint.h>

// EdgeConv: out[i] = max_k theta[src[i,k]] + feat @ (W_phi - W_theta)
// N=65536, F=512, K=16.
//
// Pipeline (3 kernels; convert kernel FUSED into gemm this round):
//  k_prep_w  : Wcat^T (1024x512) bf16, LDS-transposed; cols 512.. hold
//              (W_phi - W_theta)^T so GEMM directly produces delta
//  k_gemm    : 128x128 bf16 MFMA tile, XCD-swizzled blockIdx.
//              A staged from f32 feat directly: reg-load f32x4 x2 per row,
//              RNE cvt to bf16, ds_write_b128 to SWIZZLED slot (both-sides
//              swizzle trivially consistent since we control the write addr).
//              B staged via global_load_lds with source-col pre-swizzle.
//              2-buffer, one __syncthreads per K-step (all deeper pipelines
//              measured neutral R1-R3). Operand-swapped MFMA -> packed
//              ushort4/f32x4 epilogue. theta -> 16 slabs of [N x 32] bf16
//              (4 MB each == one XCD L2); delta f32 -> d_out.
//  k_gather  : TWO PHASE LAUNCHES (slices 0-7, then 8-15). Block b -> XCD
//              b&7 reads ONLY slice (phase*8 + b&7): per-XCD working set =
//              one 4MB slab = its L2, enforced by the kernel boundary.
//              2048 blocks/phase (256 rows x 32 cols each) = 8 blocks/CU.
//              nt delta-read/out-write.

typedef __bf16 bf16x8 __attribute__((ext_vector_type(8)));
typedef float f32x4 __attribute__((ext_vector_type(4)));
typedef unsigned short u16x8 __attribute__((ext_vector_type(8)));

__device__ __forceinline__ unsigned short f2bf(float x) {
    unsigned u = __float_as_uint(x);
    unsigned r = u + 0x7fffu + ((u >> 16) & 1u);   // RNE
    return (unsigned short)(r >> 16);
}

__device__ __forceinline__ void async_ld16(const void* g, void* l) {
    __builtin_amdgcn_global_load_lds(
        (const __attribute__((address_space(1))) unsigned int*)g,
        (__attribute__((address_space(3))) unsigned int*)l,
        16, 0, 0);
}

// ---------------- Wcat^T via LDS transpose ----------------
// wtc[n][k]:  n<512 -> Wth[k][n] ;  n>=512 -> Wph[k][n-512] - Wth[k][n-512]
__global__ void k_prep_w(const float* __restrict__ Wth,
                         const float* __restrict__ Wph,
                         unsigned short* __restrict__ wtc) {
    __shared__ float tile[32][33];
    const int k0 = (blockIdx.x & 15) * 32;
    const int n0 = (blockIdx.x >> 4) * 32;
    const int t  = threadIdx.x;
    const int cc = t & 31;
    const int r0 = t >> 5;
#pragma unroll
    for (int it = 0; it < 4; ++it) {
        const int r  = it * 8 + r0;
        const int gn = n0 + cc;
        float v;
        if (gn < 512) v = Wth[(k0 + r) * 512 + gn];
        else          v = Wph[(k0 + r) * 512 + (gn - 512)] - Wth[(k0 + r) * 512 + (gn - 512)];
        tile[r][cc] = v;
    }
    __syncthreads();
#pragma unroll
    for (int it = 0; it < 4; ++it) {
        const int r2 = t & 31;
        const int c2 = it * 8 + (t >> 5);
        wtc[(size_t)(n0 + c2) * 512 + k0 + r2] = f2bf(tile[r2][c2]);
    }
}

// ---------------- bf16 MFMA GEMM (A = f32 feat, converted in-staging) -------
// 128x128 tile, BK=32, 256 thr = 4 waves (2x2 of 64x64), 16x16x32 MFMA.
__global__ __launch_bounds__(256, 3)
void k_gemm(const float* __restrict__ A,            // N x 512 f32 (feat)
            const unsigned short* __restrict__ Bt,  // 1024 x 512 bf16
            unsigned short* __restrict__ theta,     // 16 slabs of N x 32
            float* __restrict__ delta_f,            // N x 512 f32
            size_t slabStride)
{
    __shared__ __align__(16) unsigned short As[2][128 * 32];
    __shared__ __align__(16) unsigned short Bs[2][128 * 32];

    const int tid  = threadIdx.x;
    const int wave = tid >> 6;
    const int lane = tid & 63;
    const int quad = lane >> 4;
    const int l15  = lane & 15;

    const int b  = blockIdx.x;
    const int mt = (b >> 6) * 8 + (b & 7);
    const int nt = (b >> 3) & 7;
    const int m0 = mt * 128;
    const int n0 = nt * 128;

    const int wm = wave >> 1;
    const int wn = wave & 1;

    f32x4 acc[4][4];
#pragma unroll
    for (int i = 0; i < 4; i++)
#pragma unroll
        for (int j = 0; j < 4; j++) acc[i][j] = (f32x4){0.f, 0.f, 0.f, 0.f};

    const int r0 = wave * 32 + (lane >> 2);     // rows staged by this wave
    const int r1 = r0 + 16;
    // Swizzled 16B slot (elems): slot (lane&3) XOR ((row>>1)&3)==((lane>>3)&3)
    // (identical for r0 and r1: +16 rows preserves (row>>1)&3).
    const int sw = (((lane & 3) ^ ((lane >> 3) & 3)) << 3);

    // A: f32 source, plain column (we write the swizzled LDS addr directly)
    const float* Ag0 = A + (size_t)(m0 + r0) * 512 + (lane & 3) * 8;
    const float* Ag1 = A + (size_t)(m0 + r1) * 512 + (lane & 3) * 8;
    // B: bf16 source, pre-swizzled column (DMA writes LDS linearly)
    const unsigned short* Bg0 = Bt + (size_t)(n0 + r0) * 512 + sw;
    const unsigned short* Bg1 = Bt + (size_t)(n0 + r1) * 512 + sw;

    // LDS write addrs (elems)
    const int wAo0 = r0 * 32 + sw;
    const int wAo1 = r1 * 32 + sw;
    const int oB0  = wave * 1024;        // DMA: wave-uniform base (+lane*16B)
    const int oB1  = wave * 1024 + 512;

    f32x4 a0lo, a0hi, a1lo, a1hi;

#define DMAB(buf, kg) do {                              \
        async_ld16(Bg0 + (kg), &Bs[(buf)][oB0]);        \
        async_ld16(Bg1 + (kg), &Bs[(buf)][oB1]);        \
    } while (0)
#define ALOAD(kg) do {                                  \
        a0lo = *(const f32x4*)(Ag0 + (kg));             \
        a0hi = *(const f32x4*)(Ag0 + (kg) + 4);         \
        a1lo = *(const f32x4*)(Ag1 + (kg));             \
        a1hi = *(const f32x4*)(Ag1 + (kg) + 4);         \
    } while (0)
#define ACVTW(buf) do {                                                       \
        u16x8 p0, p1;                                                         \
        p0[0] = f2bf(a0lo[0]); p0[1] = f2bf(a0lo[1]);                         \
        p0[2] = f2bf(a0lo[2]); p0[3] = f2bf(a0lo[3]);                         \
        p0[4] = f2bf(a0hi[0]); p0[5] = f2bf(a0hi[1]);                         \
        p0[6] = f2bf(a0hi[2]); p0[7] = f2bf(a0hi[3]);                         \
        p1[0] = f2bf(a1lo[0]); p1[1] = f2bf(a1lo[1]);                         \
        p1[2] = f2bf(a1lo[2]); p1[3] = f2bf(a1lo[3]);                         \
        p1[4] = f2bf(a1hi[0]); p1[5] = f2bf(a1hi[1]);                         \
        p1[6] = f2bf(a1hi[2]); p1[7] = f2bf(a1hi[3]);                         \
        *(u16x8*)&As[(buf)][wAo0] = p0;                                       \
        *(u16x8*)&As[(buf)][wAo1] = p1;                                       \
    } while (0)

    // prologue: stage tile 0 into buf 0
    DMAB(0, 0);
    ALOAD(0);
    ACVTW(0);
    __syncthreads();

    // Read-side swizzle: logical 16B slot `quad` at row r -> physical
    // slot quad ^ ((r>>1)&3); (r>>1)&3 == (l15>>1)&3 (r = base16 + l15).
    const int rdoff = (quad << 3) ^ (((l15 >> 1) & 3) << 3);

#pragma unroll
    for (int kt = 0; kt < 16; ++kt) {
        const int cur = kt & 1;
        if (kt < 15) {                    // issue next-tile loads early
            DMAB(cur ^ 1, (kt + 1) * 32);
            ALOAD((kt + 1) * 32);
        }

        bf16x8 af[4], bfr[4];
#pragma unroll
        for (int t = 0; t < 4; ++t) {
            const int am = wm * 64 + t * 16 + l15;
            af[t]  = *(const bf16x8*)&As[cur][am * 32 + rdoff];
            const int bn = wn * 64 + t * 16 + l15;
            bfr[t] = *(const bf16x8*)&Bs[cur][bn * 32 + rdoff];
        }
#pragma unroll
        for (int i = 0; i < 4; i++)
#pragma unroll
            for (int j = 0; j < 4; j++)
                acc[i][j] = __builtin_amdgcn_mfma_f32_16x16x32_bf16(bfr[j], af[i], acc[i][j], 0, 0, 0);

        if (kt < 15) {
            ACVTW(cur ^ 1);               // cvt waits its global loads
            __syncthreads();              // publishes A writes + B DMA (vmcnt 0)
        }
    }
#undef DMAB
#undef ALOAD
#undef ACVTW

    // Swapped D layout: m = lane&15 dim, n = quad*4 + reg dim
    const bool is_theta = (n0 < 512);
#pragma unroll
    for (int i = 0; i < 4; i++) {
        const int m = m0 + wm * 64 + i * 16 + l15;
#pragma unroll
        for (int j = 0; j < 4; j++) {
            const int nb = n0 + wn * 64 + j * 16 + quad * 4;
            const f32x4 v = acc[i][j];
            if (is_theta) {
                ushort4 o;
                o.x = f2bf(v[0]); o.y = f2bf(v[1]);
                o.z = f2bf(v[2]); o.w = f2bf(v[3]);
                *(ushort4*)&theta[(size_t)(nb >> 5) * slabStride
                                  + (size_t)m * 32 + (nb & 31)] = o;
            } else {
                *(f32x4*)&delta_f[(size_t)m * 512 + (nb - 512)] = v;
            }
        }
    }
}

// ---------------- column-sliced gather + max + combine (phase launch) -------
// grid = 8 x (N/256) per launch. Block b: xcd = b&7, chunk = b>>3;
// slice = phase*8 + xcd. 256 rows x 32 cols per block; 4 passes of 64 rows.
// Per thread: 8 cols (16 B uint4 per gather).
__global__ void k_gather(const unsigned short* __restrict__ theta,
                         float* out,                      // holds delta f32 on entry
                         const int* __restrict__ src,
                         const int* __restrict__ kptr,
                         int phase, size_t slabStride)
{
    const int b     = blockIdx.x;
    const int xcd   = b & 7;
    const int chunk = b >> 3;                    // 0 .. N/256-1
    const int slice = phase * 8 + xcd;
    const int kk    = *kptr;

    const unsigned short* slab = theta + (size_t)slice * slabStride;
    const int tid = threadIdx.x;
    const int c8  = (tid & 3) * 8;               // col within 32-wide slice
    const int rly = tid >> 2;                    // 0..63

#pragma unroll 2
    for (int pass = 0; pass < 4; ++pass) {
        const int row = chunk * 256 + pass * 64 + rly;

        float m0 = -INFINITY, m1 = -INFINITY, m2 = -INFINITY, m3 = -INFINITY;
        float m4 = -INFINITY, m5 = -INFINITY, m6 = -INFINITY, m7 = -INFINITY;

        if (kk == 16) {
            const int4* sp = (const int4*)(src + (size_t)row * 16);
            int4 sv[4];
            sv[0] = sp[0]; sv[1] = sp[1]; sv[2] = sp[2]; sv[3] = sp[3];
#pragma unroll
            for (int q = 0; q < 4; ++q) {
                const int ss[4] = {sv[q].x, sv[q].y, sv[q].z, sv[q].w};
#pragma unroll
                for (int j = 0; j < 4; ++j) {
                    const uint4 v = *(const uint4*)(slab + (size_t)ss[j] * 32 + c8);
                    m0 = fmaxf(m0, __uint_as_float(v.x << 16));
                    m1 = fmaxf(m1, __uint_as_float(v.x & 0xffff0000u));
                    m2 = fmaxf(m2, __uint_as_float(v.y << 16));
                    m3 = fmaxf(m3, __uint_as_float(v.y & 0xffff0000u));
                    m4 = fmaxf(m4, __uint_as_float(v.z << 16));
                    m5 = fmaxf(m5, __uint_as_float(v.z & 0xffff0000u));
                    m6 = fmaxf(m6, __uint_as_float(v.w << 16));
                    m7 = fmaxf(m7, __uint_as_float(v.w & 0xffff0000u));
                }
            }
        } else {
            for (int k = 0; k < kk; ++k) {
                const int s = src[(size_t)row * 16 + k];
                const uint4 v = *(const uint4*)(slab + (size_t)s * 32 + c8);
                m0 = fmaxf(m0, __uint_as_float(v.x << 16));
                m1 = fmaxf(m1, __uint_as_float(v.x & 0xffff0000u));
                m2 = fmaxf(m2, __uint_as_float(v.y << 16));
                m3 = fmaxf(m3, __uint_as_float(v.y & 0xffff0000u));
                m4 = fmaxf(m4, __uint_as_float(v.z << 16));
                m5 = fmaxf(m5, __uint_as_float(v.z & 0xffff0000u));
                m6 = fmaxf(m6, __uint_as_float(v.w << 16));
                m7 = fmaxf(m7, __uint_as_float(v.w & 0xffff0000u));
            }
        }

        float* op = out + (size_t)row * 512 + slice * 32 + c8;
        const f32x4 d0 = __builtin_nontemporal_load((const f32x4*)op);
        const f32x4 d1 = __builtin_nontemporal_load((const f32x4*)op + 1);
        f32x4 o0, o1;
        o0[0] = m0 + d0[0]; o0[1] = m1 + d0[1]; o0[2] = m2 + d0[2]; o0[3] = m3 + d0[3];
        o1[0] = m4 + d1[0]; o1[1] = m5 + d1[1]; o1[2] = m6 + d1[2]; o1[3] = m7 + d1[3];
        __builtin_nontemporal_store(o0, (f32x4*)op);
        __builtin_nontemporal_store(o1, (f32x4*)op + 1);
    }
}

extern "C" void kernel_launch(void* const* d_in, const int* in_sizes, int n_in,
                              void* d_out, int out_size, void* d_ws, size_t ws_size,
                              hipStream_t stream) {
    const int*   kptr = (const int*)d_in[0];
    const int*   src  = (const int*)d_in[1];
    const float* feat = (const float*)d_in[2];
    const float* Wth  = (const float*)d_in[3];
    const float* Wph  = (const float*)d_in[4];
    float* out = (float*)d_out;

    const int N = in_sizes[2] / 512;            // 65536
    const size_t slabStride = (size_t)N * 32;   // elems per 32-col slab

    // ws layout: wtc 1MB (at 0) | theta slabs 64MB (at 16MB)
    unsigned short* wtc   = (unsigned short*)d_ws;
    unsigned short* table = (unsigned short*)((char*)d_ws + (size_t)16 * 1024 * 1024);

    k_prep_w<<<512, 256, 0, stream>>>(Wth, Wph, wtc);
    k_gemm<<<(N / 128) * 8, 256, 0, stream>>>(feat, wtc, table, out, slabStride);
    k_gather<<<8 * (N / 256), 256, 0, stream>>>(table, out, src, kptr, 0, slabStride);
    k_gather<<<8 * (N / 256), 256, 0, stream>>>(table, out, src, kptr, 1, slabStride);
}